// Round 2
// baseline (702.734 us; speedup 1.0000x reference)
//
#include <hip/hip_runtime.h>

typedef unsigned short u16;
typedef unsigned int u32;
typedef short s8v __attribute__((ext_vector_type(8)));   // 8 x bf16 bits (4 VGPRs)
typedef float f4v __attribute__((ext_vector_type(4)));   // MFMA accumulator

// ---------- helpers ----------
__device__ __forceinline__ u16 f2bf(float f) {
    u32 u = __float_as_uint(f);
    u += 0x7FFFu + ((u >> 16) & 1u);   // round-to-nearest-even
    return (u16)(u >> 16);
}

__device__ __forceinline__ void async_load16(const u16* g, u16* l) {
    // global -> LDS DMA, 16B per lane; LDS dest = wave-uniform base + lane*16
    __builtin_amdgcn_global_load_lds(
        (const __attribute__((address_space(1))) u32*)g,
        (__attribute__((address_space(3))) u32*)l,
        16, 0, 0);
}

// ---------- kernel 1: style + demod + modulated bf16 weights ----------
// grid (256 co, 8 b), 256 threads (thread = ci)
// Wmod layout: [b][t(9)][co(256)][ci(256)] bf16
__global__ void modulate_kernel(const float* __restrict__ norm_feat,  // [8][64]
                                const float* __restrict__ mod_w,      // [256][64]
                                const float* __restrict__ mod_b,      // [256]
                                const float* __restrict__ weight,     // [256][256][9]
                                u16* __restrict__ Wmod) {
    const int co = blockIdx.x;
    const int b  = blockIdx.y;
    const int ci = threadIdx.x;

    __shared__ float nf[64];
    __shared__ float red[256];

    if (ci < 64) nf[ci] = norm_feat[b * 64 + ci];
    __syncthreads();

    float s = mod_b[ci];
    #pragma unroll 8
    for (int d = 0; d < 64; ++d) s += nf[d] * mod_w[ci * 64 + d];

    float w9[9];
    const float* wp = weight + ((size_t)co * 256 + ci) * 9;
    float sq = 0.f;
    #pragma unroll
    for (int t = 0; t < 9; ++t) { w9[t] = wp[t]; sq += w9[t] * w9[t]; }

    red[ci] = sq * s * s;
    __syncthreads();
    for (int off = 128; off > 0; off >>= 1) {
        if (ci < off) red[ci] += red[ci + off];
        __syncthreads();
    }
    const float scale = 1.0f / 48.0f;              // 1/sqrt(256*9)
    const float demod = rsqrtf(scale * scale * red[0] + 1e-8f);
    const float coef  = scale * s * demod;

    #pragma unroll
    for (int t = 0; t < 9; ++t) {
        Wmod[(((size_t)b * 9 + t) * 256 + co) * 256 + ci] = f2bf(w9[t] * coef);
    }
}

// ---------- kernel 2: NCHW fp32 -> [b][y][ciQuad(32)][x(128)][8ci] bf16 ----------
// grid (128 y, 8 b), 256 threads
__global__ void transpose_kernel(const float* __restrict__ fea,  // [8][256][128][128]
                                 u16* __restrict__ feaT) {
    __shared__ float lds_t[64][132];   // pad 132: store/read both <=2-way (free)
    const int y = blockIdx.x;
    const int b = blockIdx.y;
    const int tid = threadIdx.x;

    for (int c0 = 0; c0 < 256; c0 += 64) {
        #pragma unroll
        for (int r = 0; r < 32; ++r) {
            int i = r * 256 + tid;          // 0..8191
            int c = i >> 7;                 // 0..63
            int x = i & 127;
            lds_t[c][x] = fea[(((size_t)b * 256 + c0 + c) * 128 + y) * 128 + x];
        }
        __syncthreads();
        // emit [qq(8)][x(128)][c8(8)] as u32 units: [qq][x][c4(4)]
        #pragma unroll
        for (int it = 0; it < 16; ++it) {
            int p  = it * 256 + tid;        // 0..4095
            int c4 = p & 3;
            int x  = (p >> 2) & 127;
            int qq = p >> 9;                // 0..7
            int c  = qq * 8 + c4 * 2;
            u32 u = (u32)f2bf(lds_t[c][x]) | ((u32)f2bf(lds_t[c + 1][x]) << 16);
            u32* dst = (u32*)&feaT[((((size_t)(b * 128 + y) * 32) + (c0 >> 3) + qq) * 128 + x) * 8 + c4 * 2];
            *dst = u;
        }
        __syncthreads();
    }
}

// ---------- kernel 3: MFMA conv (shift-GEMM), 2 rows/block ----------
// grid (64 ypair, 2 cb, 8 b), 256 threads = 4 waves
// wave: mw = wave&1 (co 64-half), prow = wave>>1 (which of 2 output rows)
// each wave: 64 co x 128 px, acc 4x8 frags
__global__ __launch_bounds__(256, 2) void conv_mfma(
        const u16* __restrict__ Wmod,   // [8][9][256][256] bf16
        const u16* __restrict__ feaT,   // [8][128][32][128][8] bf16
        float* __restrict__ out) {      // [8][256][128][128]
    // slots 0..3: fea rows y0-1 .. y0+2; slot 4: permanent zero row
    // layout per slot: [quad(4)][px(130: 1..128 data, 0&129 zero)][8ci]
    __shared__ u16 lds_fea[5][4][130][8];   // 41600 B

    const int y0  = blockIdx.x * 2;
    const int cb  = blockIdx.y;
    const int b   = blockIdx.z;
    const int tid = threadIdx.x;
    const int lane = tid & 63;
    const int wave = tid >> 6;
    const int mw   = wave & 1;
    const int prow = wave >> 1;
    const int l4   = lane >> 4;      // quad 0..3
    const int l15  = lane & 15;

    // zero slot 4 (4*130*8 u16 = 2080 u32)
    {
        u32* z = (u32*)lds_fea[4];
        for (int i = tid; i < 2080; i += 256) z[i] = 0;
    }
    // zero pad columns px=0, px=129 for slots 0..3 (4 s * 4 q * 2 col * 4 u32 = 128)
    if (tid < 128) {
        int s   = tid >> 5;
        int rem = tid & 31;
        int q   = rem >> 3;
        int c3  = rem & 7;
        int col = (c3 >> 2) ? 129 : 0;
        int w   = c3 & 3;
        *(u32*)&lds_fea[s][q][col][w * 2] = 0;
    }

    // LDS slot per (prow, kh): slot = prow+kh, or 4 if source row OOB
    int rsel[3];
    #pragma unroll
    for (int kh = 0; kh < 3; ++kh) {
        int gy = y0 + prow - 1 + kh;
        rsel[kh] = ((unsigned)gy < 128u) ? (prow + kh) : 4;
    }

    f4v acc[4][8];
    #pragma unroll
    for (int i = 0; i < 4; ++i)
        #pragma unroll
        for (int j = 0; j < 8; ++j) acc[i][j] = (f4v)0.0f;

    for (int ci0 = 0; ci0 < 256; ci0 += 32) {
        __syncthreads();   // previous iteration's reads done before overwrite
        // stage 4 fea rows x 4 quads x 128 px: 32 DMA issues, 8 per wave
        #pragma unroll
        for (int i = 0; i < 8; ++i) {
            int idx  = wave + 4 * i;      // 0..31, wave-uniform
            int s    = idx >> 3;          // row slot 0..3
            int sub  = idx & 7;
            int q    = sub >> 1;          // ci quad 0..3
            int half = sub & 1;           // px half
            int gy   = y0 - 1 + s;
            if ((unsigned)gy < 128u) {
                const u16* src = feaT +
                    ((((size_t)(b * 128 + gy) * 32 + (ci0 >> 3) + q) * 128) + half * 64 + lane) * 8;
                async_load16(src, &lds_fea[s][q][1 + half * 64][0]);
            }
        }
        __syncthreads();

        #pragma unroll
        for (int t = 0; t < 9; ++t) {
            const int kh = t / 3, kw = t % 3;
            const int r = rsel[kh];
            s8v afr[4], bfr[8];
            #pragma unroll
            for (int i = 0; i < 4; ++i) {
                const u16* ap = Wmod +
                    ((((size_t)b * 9 + t) * 256 + cb * 128 + mw * 64 + i * 16 + l15) * 256
                     + ci0 + l4 * 8);
                afr[i] = *(const s8v*)ap;
            }
            #pragma unroll
            for (int j = 0; j < 8; ++j) {
                // quarter-wave (uniform l4): 16 consecutive px -> 256B contiguous, conflict-free
                bfr[j] = *(const s8v*)&lds_fea[r][l4][j * 16 + l15 + kw][0];
            }
            #pragma unroll
            for (int i = 0; i < 4; ++i)
                #pragma unroll
                for (int j = 0; j < 8; ++j)
                    acc[i][j] = __builtin_amdgcn_mfma_f32_16x16x32_bf16(
                        afr[i], bfr[j], acc[i][j], 0, 0, 0);
        }
    }

    // epilogue: C/D col=lane&15 (px), row=quad*4+reg (co)
    const int y = y0 + prow;
    const int co_base = cb * 128 + mw * 64 + l4 * 4;
    #pragma unroll
    for (int i = 0; i < 4; ++i) {
        #pragma unroll
        for (int reg = 0; reg < 4; ++reg) {
            int co = co_base + i * 16 + reg;
            float* op = out + (((size_t)(b * 256 + co) * 128 + y) * 128 + l15);
            #pragma unroll
            for (int j = 0; j < 8; ++j) op[j * 16] = acc[i][j][reg];
        }
    }
}

// ---------- launch ----------
extern "C" void kernel_launch(void* const* d_in, const int* in_sizes, int n_in,
                              void* d_out, int out_size, void* d_ws, size_t ws_size,
                              hipStream_t stream) {
    const float* fea       = (const float*)d_in[0];
    const float* norm_feat = (const float*)d_in[1];
    const float* mod_w     = (const float*)d_in[2];
    const float* mod_b     = (const float*)d_in[3];
    const float* weight    = (const float*)d_in[4];
    float* out = (float*)d_out;

    // workspace: Wmod bf16 = 9 MiB, then feaT bf16 = 64 MiB
    u16* Wmod = (u16*)d_ws;
    u16* feaT = (u16*)((char*)d_ws + 9u * 1024u * 1024u);

    modulate_kernel<<<dim3(256, 8), 256, 0, stream>>>(norm_feat, mod_w, mod_b, weight, Wmod);
    transpose_kernel<<<dim3(128, 8), 256, 0, stream>>>(fea, feaT);
    conv_mfma<<<dim3(64, 2, 8), 256, 0, stream>>>(Wmod, feaT, out);
}

// Round 3
// 584.524 us; speedup vs baseline: 1.2022x; 1.2022x over previous
//
#include <hip/hip_runtime.h>

typedef unsigned short u16;
typedef unsigned int u32;
typedef short s8v __attribute__((ext_vector_type(8)));   // 8 x bf16 bits (4 VGPRs)
typedef float f4v __attribute__((ext_vector_type(4)));   // MFMA accumulator

// ---------- helpers ----------
__device__ __forceinline__ u16 f2bf(float f) {
    u32 u = __float_as_uint(f);
    u += 0x7FFFu + ((u >> 16) & 1u);   // round-to-nearest-even
    return (u16)(u >> 16);
}

__device__ __forceinline__ void async_load16(const u16* g, u16* l) {
    // global -> LDS DMA, 16B per lane; LDS dest = wave-uniform base + lane*16
    __builtin_amdgcn_global_load_lds(
        (const __attribute__((address_space(1))) u32*)g,
        (__attribute__((address_space(3))) u32*)l,
        16, 0, 0);
}

// ---------- kernel 0: style (once per b, coalesced mod_w via LDS) ----------
// grid (8 b), 256 threads (thread = ci)
__global__ void style_kernel(const float* __restrict__ norm_feat,  // [8][64]
                             const float* __restrict__ mod_w,      // [256][64]
                             const float* __restrict__ mod_b,      // [256]
                             float* __restrict__ style) {          // [8][256]
    __shared__ float nf[64];
    __shared__ float mw[256][65];   // +1 pad: compute-phase reads spread banks
    const int b = blockIdx.x;
    const int tid = threadIdx.x;

    if (tid < 64) nf[tid] = norm_feat[b * 64 + tid];
    #pragma unroll
    for (int i = 0; i < 64; ++i) {
        int idx = i * 256 + tid;        // coalesced over mod_w
        mw[idx >> 6][idx & 63] = mod_w[idx];
    }
    __syncthreads();

    float s = mod_b[tid];
    #pragma unroll 8
    for (int d = 0; d < 64; ++d) s += nf[d] * mw[tid][d];
    style[b * 256 + tid] = s;
}

// ---------- kernel 1: demod + modulated bf16 weights ----------
// grid (256 co, 8 b), 256 threads (thread = ci)
// Wmod layout: [b][t(9)][co(256)][ci(256)] bf16
__global__ void modulate_kernel(const float* __restrict__ style,   // [8][256]
                                const float* __restrict__ weight,  // [256][256][9]
                                u16* __restrict__ Wmod) {
    const int co = blockIdx.x;
    const int b  = blockIdx.y;
    const int ci = threadIdx.x;

    __shared__ float red[256];

    const float s = style[b * 256 + ci];   // coalesced, L2-hot

    float w9[9];
    const float* wp = weight + ((size_t)co * 256 + ci) * 9;
    float sq = 0.f;
    #pragma unroll
    for (int t = 0; t < 9; ++t) { w9[t] = wp[t]; sq += w9[t] * w9[t]; }

    red[ci] = sq * s * s;
    __syncthreads();
    for (int off = 128; off > 0; off >>= 1) {
        if (ci < off) red[ci] += red[ci + off];
        __syncthreads();
    }
    const float scale = 1.0f / 48.0f;              // 1/sqrt(256*9)
    const float demod = rsqrtf(scale * scale * red[0] + 1e-8f);
    const float coef  = scale * s * demod;

    #pragma unroll
    for (int t = 0; t < 9; ++t) {
        Wmod[(((size_t)b * 9 + t) * 256 + co) * 256 + ci] = f2bf(w9[t] * coef);
    }
}

// ---------- kernel 2: NCHW fp32 -> NHWC bf16 ----------
// grid (128 y, 8 b), 256 threads
__global__ void transpose_kernel(const float* __restrict__ fea,  // [8][256][128][128]
                                 u16* __restrict__ feaT) {       // [8][128][128][256]
    __shared__ float lds_t[64][129];
    const int y = blockIdx.x;
    const int b = blockIdx.y;
    const int tid = threadIdx.x;

    for (int c0 = 0; c0 < 256; c0 += 64) {
        #pragma unroll
        for (int r = 0; r < 32; ++r) {
            int i = r * 256 + tid;          // 0..8191
            int c = i >> 7;                 // 0..63
            int x = i & 127;
            lds_t[c][x] = fea[(((size_t)b * 256 + c0 + c) * 128 + y) * 128 + x];
        }
        __syncthreads();
        #pragma unroll
        for (int j = 0; j < 16; ++j) {
            int p  = j * 256 + tid;         // 0..4095 (32 c-pairs x 128 x)
            int cp = p & 31;
            int x  = p >> 5;
            int cl = cp * 2;
            float f0 = lds_t[cl][x];
            float f1 = lds_t[cl + 1][x];
            u32 u = (u32)f2bf(f0) | ((u32)f2bf(f1) << 16);
            *(u32*)&feaT[(((size_t)b * 128 + y) * 128 + x) * 256 + c0 + cl] = u;
        }
        __syncthreads();
    }
}

// ---------- kernel 3: MFMA conv (shift-GEMM) — R1 structure (anchor) ----------
// grid (128 y, 2 co-blocks, 8 b), 256 threads = 4 waves
__global__ __launch_bounds__(256) void conv_mfma(
        const u16* __restrict__ Wmod,   // [8][9][256][256] bf16
        const u16* __restrict__ feaT,   // [8][128][128][256] bf16
        float* __restrict__ out) {      // [8][256][128][128]
    // rows 0..2: fea rows y-1..y+1 (x index shifted +1, cols 0 and 129 are zero pad)
    // row 3: permanent zero row for out-of-bounds y
    __shared__ u16 lds_fea[4][130][32];

    const int y   = blockIdx.x;
    const int cb  = blockIdx.y;
    const int b   = blockIdx.z;
    const int tid = threadIdx.x;
    const int lane = tid & 63;
    const int wave = tid >> 6;
    const int mw = wave & 1;        // co half (64)
    const int nw = wave >> 1;       // pixel half (64)
    const int l4  = lane >> 4;      // quad 0..3
    const int l15 = lane & 15;

    // init zero row + pad columns (persist across whole kernel)
    for (int i = tid; i < 130 * 32; i += 256) ((u16*)lds_fea[3])[i] = 0;
    if (tid < 192) {
        int r   = tid / 64;                       // 0..2
        int col = ((tid >> 5) & 1) ? 129 : 0;
        lds_fea[r][col][tid & 31] = 0;
    }

    const int rsel[3] = { (y == 0) ? 3 : 0, 1, (y == 127) ? 3 : 2 };

    f4v acc[4][4];
    #pragma unroll
    for (int i = 0; i < 4; ++i)
        #pragma unroll
        for (int j = 0; j < 4; ++j) acc[i][j] = (f4v)0.0f;

    const int dma_x  = lane >> 2;         // 0..15
    const int dma_ci = (lane & 3) * 8;    // 0,8,16,24

    for (int ci0 = 0; ci0 < 256; ci0 += 32) {
        __syncthreads();   // previous iteration's reads done before overwrite
        // stage fea chunk: 3 rows x 128 x x 32 ci, bf16, via global->LDS DMA
        #pragma unroll
        for (int i = 0; i < 6; ++i) {
            int q  = wave + 4 * i;        // 0..23, wave-uniform
            int r  = q >> 3;              // 0..2
            int xb = q & 7;               // 0..7
            int gy = y - 1 + r;
            if ((unsigned)gy < 128u) {
                int x = xb * 16 + dma_x;
                const u16* g = feaT + ((((size_t)b * 128 + gy) * 128 + x) * 256 + ci0 + dma_ci);
                async_load16(g, &lds_fea[r][1 + xb * 16][0]);
            }
        }
        __syncthreads();

        #pragma unroll
        for (int t = 0; t < 9; ++t) {
            const int kh = t / 3, kw = t % 3;
            const int r = rsel[kh];
            s8v afr[4], bfr[4];
            #pragma unroll
            for (int i = 0; i < 4; ++i) {
                const u16* ap = Wmod +
                    ((((size_t)b * 9 + t) * 256 + cb * 128 + mw * 64 + i * 16 + l15) * 256
                     + ci0 + l4 * 8);
                afr[i] = *(const s8v*)ap;
            }
            #pragma unroll
            for (int j = 0; j < 4; ++j) {
                bfr[j] = *(const s8v*)&lds_fea[r][nw * 64 + j * 16 + l15 + kw][l4 * 8];
            }
            #pragma unroll
            for (int i = 0; i < 4; ++i)
                #pragma unroll
                for (int j = 0; j < 4; ++j)
                    acc[i][j] = __builtin_amdgcn_mfma_f32_16x16x32_bf16(
                        afr[i], bfr[j], acc[i][j], 0, 0, 0);
        }
    }

    // epilogue: C/D layout col=lane&15 (pixel), row=quad*4+reg (co)
    const int co_base = cb * 128 + mw * 64 + l4 * 4;
    const int x_base  = nw * 64 + l15;
    #pragma unroll
    for (int i = 0; i < 4; ++i) {
        #pragma unroll
        for (int reg = 0; reg < 4; ++reg) {
            int co = co_base + i * 16 + reg;
            float* op = out + (((size_t)(b * 256 + co) * 128 + y) * 128 + x_base);
            #pragma unroll
            for (int j = 0; j < 4; ++j) op[j * 16] = acc[i][j][reg];
        }
    }
}

// ---------- launch ----------
extern "C" void kernel_launch(void* const* d_in, const int* in_sizes, int n_in,
                              void* d_out, int out_size, void* d_ws, size_t ws_size,
                              hipStream_t stream) {
    const float* fea       = (const float*)d_in[0];
    const float* norm_feat = (const float*)d_in[1];
    const float* mod_w     = (const float*)d_in[2];
    const float* mod_b     = (const float*)d_in[3];
    const float* weight    = (const float*)d_in[4];
    float* out = (float*)d_out;

    // workspace: Wmod bf16 = 9 MiB, then feaT bf16 = 64 MiB.
    // style (8 KiB fp32) lives at the head of the feaT region: written by
    // style_kernel, consumed by modulate_kernel, then overwritten by
    // transpose_kernel later in the same stream (serialized) — no extra ws.
    u16* Wmod = (u16*)d_ws;
    u16* feaT = (u16*)((char*)d_ws + 9u * 1024u * 1024u);
    float* style = (float*)feaT;

    style_kernel<<<dim3(8), 256, 0, stream>>>(norm_feat, mod_w, mod_b, style);
    modulate_kernel<<<dim3(256, 8), 256, 0, stream>>>(style, weight, Wmod);
    transpose_kernel<<<dim3(128, 8), 256, 0, stream>>>(fea, feaT);
    conv_mfma<<<dim3(128, 2, 8), 256, 0, stream>>>(Wmod, feaT, out);
}